// Round 7
// baseline (437.610 us; speedup 1.0000x reference)
//
#include <hip/hip_runtime.h>
#include <cstdint>
#include <cstddef>

#define H 1024
#define BB 8
#define SS 2048
#define MROWS (BB*SS)   // 16384

typedef float  f32x4 __attribute__((ext_vector_type(4)));
typedef short  s16x8 __attribute__((ext_vector_type(8)));
typedef unsigned short u16x4 __attribute__((ext_vector_type(4)));
typedef unsigned short u16x8 __attribute__((ext_vector_type(8)));

__device__ __forceinline__ float b2f(unsigned short u) {
  union { unsigned int i; float f; } x; x.i = ((unsigned int)u) << 16; return x.f;
}
__device__ __forceinline__ unsigned short f2b(float f) {
  union { float f; unsigned int i; } x; x.f = f;
  unsigned int r = x.i + 0x7FFFu + ((x.i >> 16) & 1u);
  return (unsigned short)(r >> 16);
}

typedef __attribute__((address_space(1))) unsigned int guint;
typedef __attribute__((address_space(3))) unsigned int luint;
__device__ __forceinline__ void gld_lds16(const void* g, void* l) {
  __builtin_amdgcn_global_load_lds((guint*)g, (luint*)l, 16, 0, 0);
}

// ---------------- norms + scale + cast to bf16 ----------------
__global__ void norms_cast(const float* __restrict__ X, unsigned short* __restrict__ Xs,
                           float* __restrict__ norms) {
  const int row  = blockIdx.x * 4 + (threadIdx.x >> 6);
  const int lane = threadIdx.x & 63;
  const float4* xr = (const float4*)(X + (size_t)row * H);
  float4 d[4]; float s = 0.f;
#pragma unroll
  for (int j = 0; j < 4; ++j) {
    d[j] = xr[lane + j * 64];
    s += d[j].x*d[j].x + d[j].y*d[j].y + d[j].z*d[j].z + d[j].w*d[j].w;
  }
#pragma unroll
  for (int o = 32; o; o >>= 1) s += __shfl_xor(s, o);
  const float nrm = sqrtf(s);
  const float inv = 1.f / (nrm + 1e-9f);
  if (lane == 0) norms[row] = nrm;
  unsigned short* xo = Xs + (size_t)row * H;
#pragma unroll
  for (int j = 0; j < 4; ++j) {
    u16x4 o4;
    o4[0] = f2b(d[j].x * inv); o4[1] = f2b(d[j].y * inv);
    o4[2] = f2b(d[j].z * inv); o4[3] = f2b(d[j].w * inv);
    *(u16x4*)(xo + (size_t)(lane + j * 64) * 4) = o4;
  }
}

// ---------------- elementwise cast ----------------
__global__ void cast_f32_bf16(const float* __restrict__ in, unsigned short* __restrict__ out) {
  const size_t i = ((size_t)blockIdx.x * 256 + threadIdx.x) * 4;
  float4 d = *(const float4*)(in + i);
  u16x4 o; o[0] = f2b(d.x); o[1] = f2b(d.y); o[2] = f2b(d.z); o[3] = f2b(d.w);
  *(u16x4*)(out + i) = o;
}

// ---------------- transpose fp32 -> bf16 (anomaly matrix) ----------------
__global__ void transpose_cast_f32(const float* __restrict__ in, unsigned short* __restrict__ out) {
  __shared__ float t[32][33];
  const int c0 = blockIdx.x * 32, r0 = blockIdx.y * 32;
  const int tx = threadIdx.x, ty = threadIdx.y;
#pragma unroll
  for (int j = 0; j < 4; ++j)
    t[ty + j * 8][tx] = in[(size_t)(r0 + ty + j * 8) * H + c0 + tx];
  __syncthreads();
#pragma unroll
  for (int j = 0; j < 4; ++j)
    out[(size_t)(c0 + ty + j * 8) * H + r0 + tx] = f2b(t[tx][ty + j * 8]);
}

// ---------------- batched bf16 transpose (v -> vT per batch) ----------------
__global__ void transpose_bf16(const unsigned short* __restrict__ in, unsigned short* __restrict__ out) {
  __shared__ unsigned short t[32][33];
  const size_t zo = (size_t)blockIdx.z * SS * H;
  const int c0 = blockIdx.x * 32, r0 = blockIdx.y * 32;
  const int tx = threadIdx.x, ty = threadIdx.y;
#pragma unroll
  for (int j = 0; j < 4; ++j)
    t[ty + j * 8][tx] = in[zo + (size_t)(r0 + ty + j * 8) * H + c0 + tx];
  __syncthreads();
#pragma unroll
  for (int j = 0; j < 4; ++j)
    out[zo + (size_t)(c0 + ty + j * 8) * SS + r0 + tx] = t[tx][ty + j * 8];
}

// ---------------- NT GEMM, 128x128 tile, BK=32, 4-deep ring, reg-dbuf, 2 blocks/CU ------
// C[m,n] = sum_k A[m,k]*B[n,k]. 256 threads = 4 waves (2x2 of 64x64), acc[4][4] = 64 AGPR.
// LDS = 4 bufs x (A+B) x 128x32 bf16 = 64 KiB -> 2 blocks/CU (cross-block m114 overlap).
// Regs ~160 <= 256 budget -> NO spills (spilled scratch ops would corrupt the vmcnt ledger).
// Iter t: vmcnt(4) [tile t+1 landed; t+2 in flight]; barrier; ds_read frags of t+1 into the
// OTHER reg set; STAGE(t+3); 32... 16 MFMA on tile t's regs (reads drain under the burst).
// WAR: window between barriers touches buf (t+1)&3 [reads] and (t+3)&3 [writes] - disjoint;
// prior reader of (t+3)&3 was iter t-1's MMA whose lgkm-drain precedes barrier(t).
// LDS swizzle: slot ^= (row>>1)&3 (2 lanes/bank = free); source pre-swizzled (rule 21),
// gld_lds dest linear in tid order. Manual 2x unroll keeps reg-set indices static (rule 20).
// EPI: 0 = bf16 + bias[col]; 1 = bf16; 2 = bf16 exp(val/32); 3 = f32 * norms[row]*rs[row]
template <int EPI, int TK>   // TK = K/32, must be >= 4 and even
__global__ __launch_bounds__(256, 2)
void gemm_nt(const unsigned short* __restrict__ A, int lda,
             const unsigned short* __restrict__ B0, int ldb, long sB,
             void* __restrict__ Cv, int ldc,
             const float* __restrict__ bias,
             const float* __restrict__ norms, const float* __restrict__ rs) {
  __shared__ __align__(16) unsigned short lds[4][2][128 * 32];  // 64 KiB
  const int tid = threadIdx.x, lane = tid & 63, w = tid >> 6;

  // bijective XCD swizzle (all grids have nwg % 8 == 0)
  const int nx = gridDim.x;
  int bid = blockIdx.y * nx + blockIdx.x;
  bid = (bid & 7) * ((nx * (int)gridDim.y) >> 3) + (bid >> 3);
  const int bn = bid % nx, bm = bid / nx;

  const unsigned short* Ap = A  + (size_t)bm * 128 * lda;
  const unsigned short* Bp = B0 + (size_t)(bm >> 4) * sB + (size_t)bn * 128 * ldb;  // 16 M-tiles/batch

  // staging: thread -> (row = tid>>2 in [0,64), slot = tid&3); source slot pre-swizzled so
  // LDS[r][s] = G[r][s ^ ((r>>1)&3)] with linear LDS dest. Row r+64 has same (r>>1)&3.
  const int sr    = tid >> 2;
  const int gslot = (tid & 3) ^ ((sr >> 1) & 3);
  const unsigned short* As0 = Ap + (size_t)sr * lda + gslot * 8;
  const unsigned short* Bs0 = Bp + (size_t)sr * ldb + gslot * 8;

  auto STAGE = [&](int kt) {
    const unsigned short* as = As0 + kt * 32;
    const unsigned short* bs = Bs0 + kt * 32;
    unsigned short* la = &lds[kt & 3][0][0] + tid * 8;
    unsigned short* lb = &lds[kt & 3][1][0] + tid * 8;
    gld_lds16(as,                    la);
    gld_lds16(as + (size_t)64 * lda, la + 2048);
    gld_lds16(bs,                    lb);
    gld_lds16(bs + (size_t)64 * ldb, lb + 2048);
  };

  const int wm = w >> 1, wn = w & 1;       // 2 x 2 wave grid, 64x64 each
  const int rA = lane & 15;
  const int ssw = ((lane >> 4) ^ ((rA >> 1) & 3)) * 8;  // swizzled k-slot (ushort offset)

  s16x8 afA[4], bfA[4], afB[4], bfB[4];
  f32x4 acc[4][4] = {};

  auto READ = [&](int kt, s16x8* af, s16x8* bf) {
    const unsigned short* pa = &lds[kt & 3][0][0] + (size_t)(wm * 64 + rA) * 32 + ssw;
    const unsigned short* pb = &lds[kt & 3][1][0] + (size_t)(wn * 64 + rA) * 32 + ssw;
#pragma unroll
    for (int i = 0; i < 4; ++i) af[i] = *(const s16x8*)(pa + i * 512);
#pragma unroll
    for (int j = 0; j < 4; ++j) bf[j] = *(const s16x8*)(pb + j * 512);
  };
  auto MMA = [&](const s16x8* af, const s16x8* bf) {
    __builtin_amdgcn_s_setprio(1);
#pragma unroll
    for (int i = 0; i < 4; ++i)
#pragma unroll
      for (int j = 0; j < 4; ++j)
        acc[i][j] = __builtin_amdgcn_mfma_f32_16x16x32_bf16(af[i], bf[j], acc[i][j], 0, 0, 0);
    __builtin_amdgcn_s_setprio(0);
  };
  auto ITER = [&](int t, const s16x8* curA, const s16x8* curB, s16x8* nxtA, s16x8* nxtB) {
    if (t <= TK - 3)      asm volatile("s_waitcnt vmcnt(4)" ::: "memory");
    else if (t == TK - 2) asm volatile("s_waitcnt vmcnt(0)" ::: "memory");
    __builtin_amdgcn_s_barrier();
    if (t + 1 < TK) READ(t + 1, nxtA, nxtB);
    if (t + 3 < TK) STAGE(t + 3);
    MMA(curA, curB);
  };

  // prologue: 3 tiles in flight; tile 0 landed; frags(0) -> set A
  STAGE(0); STAGE(1); STAGE(2);
  asm volatile("s_waitcnt vmcnt(8)" ::: "memory");
  __builtin_amdgcn_s_barrier();
  READ(0, afA, bfA);

#pragma unroll 1
  for (int t = 0; t < TK; t += 2) {
    ITER(t,     afA, bfA, afB, bfB);
    ITER(t + 1, afB, bfB, afA, bfA);
  }

  // epilogue: C/D layout col = lane&15, row = (lane>>4)*4 + reg (m89/m91)
  const int r0b = bm * 128 + wm * 64 + (lane >> 4) * 4;
  const int c0b = bn * 128 + wn * 64 + rA;
#pragma unroll
  for (int i = 0; i < 4; ++i) {
#pragma unroll
    for (int j = 0; j < 4; ++j) {
      const int cc = c0b + j * 16;
#pragma unroll
      for (int r = 0; r < 4; ++r) {
        const int rr = r0b + i * 16 + r;
        const size_t idx = (size_t)rr * ldc + cc;
        const float val = acc[i][j][r];
        if constexpr (EPI == 0) {
          ((unsigned short*)Cv)[idx] = f2b(val + bias[cc]);
        } else if constexpr (EPI == 1) {
          ((unsigned short*)Cv)[idx] = f2b(val);
        } else if constexpr (EPI == 2) {
          // P = exp(s/32) directly: |s/32| <= ~0.5 by magnitude analysis, no max needed;
          // normalization folds into PV epilogue via rs[row].
          ((unsigned short*)Cv)[idx] = f2b(__expf(val * 0.03125f));
        } else {
          ((float*)Cv)[idx] = val * norms[rr] * rs[rr];
        }
      }
    }
  }
}

// ---------------- row sum of P (unnormalized exp), rs = 1/sum ----------------
__global__ void rowsum(const unsigned short* __restrict__ S, float* __restrict__ rs) {
  const int row = blockIdx.x;
  const int tid = threadIdx.x, lane = tid & 63, w = tid >> 6;
  const unsigned short* sr = S + (size_t)row * SS;
  u16x8 raw = *(const u16x8*)(sr + tid * 8);
  float s = 0.f;
#pragma unroll
  for (int j = 0; j < 8; ++j) s += b2f(raw[j]);
#pragma unroll
  for (int o = 32; o; o >>= 1) s += __shfl_xor(s, o);
  __shared__ float sm[4];
  if (lane == 0) sm[w] = s;
  __syncthreads();
  if (tid == 0) rs[row] = 1.0f / (sm[0] + sm[1] + sm[2] + sm[3]);
}

extern "C" void kernel_launch(void* const* d_in, const int* in_sizes, int n_in,
                              void* d_out, int out_size, void* d_ws, size_t ws_size,
                              hipStream_t stream) {
  (void)in_sizes; (void)n_in; (void)out_size; (void)ws_size;
  const float* X  = (const float*)d_in[0];
  const float* Wq = (const float*)d_in[1];
  const float* bq = (const float*)d_in[2];
  const float* Wv = (const float*)d_in[3];
  const float* bv = (const float*)d_in[4];
  const float* Am = (const float*)d_in[5];

  char* ws = (char*)d_ws;
  size_t off = 0;
  auto alloc = [&](size_t bytes) { char* p = ws + off; off += (bytes + 255) & ~255ull; return p; };
  float* norms          = (float*)alloc((size_t)MROWS * 4);
  float* rs             = (float*)alloc((size_t)MROWS * 4);
  unsigned short* Wqb   = (unsigned short*)alloc((size_t)H * H * 2);
  unsigned short* Wvb   = (unsigned short*)alloc((size_t)H * H * 2);
  unsigned short* Atb   = (unsigned short*)alloc((size_t)H * H * 2);
  unsigned short* Qb    = (unsigned short*)alloc((size_t)MROWS * H * 2);
  unsigned short* TQb   = (unsigned short*)alloc((size_t)MROWS * H * 2);
  unsigned short* VTb   = (unsigned short*)alloc((size_t)MROWS * H * 2);
  unsigned short* Xs    = (unsigned short*)alloc((size_t)MROWS * H * 2);  // dead after v GEMM
  unsigned short* Vb    = (unsigned short*)alloc((size_t)MROWS * H * 2);  // dead after transpose
  unsigned short* Sc    = Xs;  // scores [16384][2048] bf16 aliases Xs+Vb (64 MB), live later

  // 1) norms + scaled cast
  norms_cast<<<MROWS / 4, 256, 0, stream>>>(X, Xs, norms);
  // 2) weight casts + A^T
  cast_f32_bf16<<<H * H / 1024, 256, 0, stream>>>(Wq, Wqb);
  cast_f32_bf16<<<H * H / 1024, 256, 0, stream>>>(Wv, Wvb);
  transpose_cast_f32<<<dim3(H / 32, H / 32), dim3(32, 8), 0, stream>>>(Am, Atb);
  // 3) q = Xs @ Wq^T + bq ; v = Xs @ Wv^T + bv   (grid 8x128 = 1024 blocks)
  gemm_nt<0, 32><<<dim3(H / 128, MROWS / 128), 256, 0, stream>>>(Xs, H, Wqb, H, 0, Qb, H, bq, nullptr, nullptr);
  gemm_nt<0, 32><<<dim3(H / 128, MROWS / 128), 256, 0, stream>>>(Xs, H, Wvb, H, 0, Vb, H, bv, nullptr, nullptr);
  // 4) vT per batch
  transpose_bf16<<<dim3(H / 32, SS / 32, BB), dim3(32, 8), 0, stream>>>(Vb, VTb);
  // 5) tq = q @ A  (via A^T, NT)
  gemm_nt<1, 32><<<dim3(H / 128, MROWS / 128), 256, 0, stream>>>(Qb, H, Atb, H, 0, TQb, H, nullptr, nullptr, nullptr);
  // 6) P = exp(q @ tq^T / 32)  (batched via strideB; exp fused in epilogue; 16x128 blocks)
  gemm_nt<2, 32><<<dim3(SS / 128, MROWS / 128), 256, 0, stream>>>(Qb, H, TQb, H, (long)SS * H, Sc, SS, nullptr, nullptr, nullptr);
  // 7) rs[row] = 1 / rowsum(P)
  rowsum<<<MROWS, 256, 0, stream>>>(Sc, rs);
  // 8) out = (P @ vT^T) * norm[row] * rs[row]   (K = 2048 -> TK = 64)
  gemm_nt<3, 64><<<dim3(H / 128, MROWS / 128), 256, 0, stream>>>(Sc, SS, VTb, SS, (long)H * SS, d_out, H, nullptr, norms, rs);
}

// Round 12
// 379.313 us; speedup vs baseline: 1.1537x; 1.1537x over previous
//
#include <hip/hip_runtime.h>
#include <cstdint>
#include <cstddef>

#define H 1024
#define BB 8
#define SS 2048
#define MROWS (BB*SS)   // 16384

typedef float  f32x4 __attribute__((ext_vector_type(4)));
typedef short  s16x8 __attribute__((ext_vector_type(8)));
typedef unsigned short u16x4 __attribute__((ext_vector_type(4)));
typedef unsigned short u16x8 __attribute__((ext_vector_type(8)));

__device__ __forceinline__ float b2f(unsigned short u) {
  union { unsigned int i; float f; } x; x.i = ((unsigned int)u) << 16; return x.f;
}
__device__ __forceinline__ unsigned short f2b(float f) {
  union { float f; unsigned int i; } x; x.f = f;
  unsigned int r = x.i + 0x7FFFu + ((x.i >> 16) & 1u);
  return (unsigned short)(r >> 16);
}

typedef __attribute__((address_space(1))) unsigned int guint;
typedef __attribute__((address_space(3))) unsigned int luint;
__device__ __forceinline__ void gld_lds16(const void* g, void* l) {
  __builtin_amdgcn_global_load_lds((guint*)g, (luint*)l, 16, 0, 0);
}

// ---------------- norms + scale + cast to bf16 ----------------
__global__ void norms_cast(const float* __restrict__ X, unsigned short* __restrict__ Xs,
                           float* __restrict__ norms) {
  const int row  = blockIdx.x * 4 + (threadIdx.x >> 6);
  const int lane = threadIdx.x & 63;
  const float4* xr = (const float4*)(X + (size_t)row * H);
  float4 d[4]; float s = 0.f;
#pragma unroll
  for (int j = 0; j < 4; ++j) {
    d[j] = xr[lane + j * 64];
    s += d[j].x*d[j].x + d[j].y*d[j].y + d[j].z*d[j].z + d[j].w*d[j].w;
  }
#pragma unroll
  for (int o = 32; o; o >>= 1) s += __shfl_xor(s, o);
  const float nrm = sqrtf(s);
  const float inv = 1.f / (nrm + 1e-9f);
  if (lane == 0) norms[row] = nrm;
  unsigned short* xo = Xs + (size_t)row * H;
#pragma unroll
  for (int j = 0; j < 4; ++j) {
    u16x4 o4;
    o4[0] = f2b(d[j].x * inv); o4[1] = f2b(d[j].y * inv);
    o4[2] = f2b(d[j].z * inv); o4[3] = f2b(d[j].w * inv);
    *(u16x4*)(xo + (size_t)(lane + j * 64) * 4) = o4;
  }
}

// ---------------- elementwise cast ----------------
__global__ void cast_f32_bf16(const float* __restrict__ in, unsigned short* __restrict__ out) {
  const size_t i = ((size_t)blockIdx.x * 256 + threadIdx.x) * 4;
  float4 d = *(const float4*)(in + i);
  u16x4 o; o[0] = f2b(d.x); o[1] = f2b(d.y); o[2] = f2b(d.z); o[3] = f2b(d.w);
  *(u16x4*)(out + i) = o;
}

// ---------------- transpose fp32 -> bf16 (anomaly matrix) ----------------
__global__ void transpose_cast_f32(const float* __restrict__ in, unsigned short* __restrict__ out) {
  __shared__ float t[32][33];
  const int c0 = blockIdx.x * 32, r0 = blockIdx.y * 32;
  const int tx = threadIdx.x, ty = threadIdx.y;
#pragma unroll
  for (int j = 0; j < 4; ++j)
    t[ty + j * 8][tx] = in[(size_t)(r0 + ty + j * 8) * H + c0 + tx];
  __syncthreads();
#pragma unroll
  for (int j = 0; j < 4; ++j)
    out[(size_t)(c0 + ty + j * 8) * H + r0 + tx] = f2b(t[tx][ty + j * 8]);
}

// ---------------- batched bf16 transpose (v -> vT per batch) ----------------
__global__ void transpose_bf16(const unsigned short* __restrict__ in, unsigned short* __restrict__ out) {
  __shared__ unsigned short t[32][33];
  const size_t zo = (size_t)blockIdx.z * SS * H;
  const int c0 = blockIdx.x * 32, r0 = blockIdx.y * 32;
  const int tx = threadIdx.x, ty = threadIdx.y;
#pragma unroll
  for (int j = 0; j < 4; ++j)
    t[ty + j * 8][tx] = in[zo + (size_t)(r0 + ty + j * 8) * H + c0 + tx];
  __syncthreads();
#pragma unroll
  for (int j = 0; j < 4; ++j)
    out[zo + (size_t)(c0 + ty + j * 8) * SS + r0 + tx] = t[tx][ty + j * 8];
}

// ---------------- NT GEMM, 256x256 tile, BK=32, 4-deep LDS ring, counted vmcnt ----------------
// Round-4 proven skeleton (951 TF): per iter t: STAGE(t+2) -> vmcnt(8) -> s_barrier ->
// COMPUTE(t). ONE barrier/K-tile; vmcnt never 0 until tail. COMPUTE interleaves ds_reads
// with MFMA clusters at source level (no pinned lgkmcnt(0)) so the compiler can emit
// progressive lgkmcnt and the LDS port drains under the MFMA bursts.
// WAR proof (1 barrier/iter): last reader of buf (t+2)&3 was COMPUTE(t-2), whose reads are
// MFMA-consumed (compiler lgkm waits) before that wave reaches barrier(t-1); the overwriting
// STAGE issues after barrier(t-1). A wave racing past COMPUTE(t) only issues STAGE(t+3)
// (buf (t+3)&3) while laggards read buf t&3 — disjoint.
// LDS swizzle: slot ^= (row>>1)&3 (2 lanes/bank = free); source pre-swizzled (rule 21),
// gld_lds dest linear (= tid order).
// EPI: 0 = bf16 + bias[cc], split output (cc<1024 -> Cv, else Cv2, col cc&1023);
//      1 = bf16; 2 = bf16 exp(val/32); 3 = f32 * norms[row]*rs[row]
template <int EPI, int TK>   // TK = K/32, must be >= 3
__global__ __launch_bounds__(512, 2)
void gemm_nt(const unsigned short* __restrict__ A, int lda,
             const unsigned short* __restrict__ B0, int ldb, long sB,
             void* __restrict__ Cv, void* __restrict__ Cv2, int ldc,
             const float* __restrict__ bias,
             const float* __restrict__ norms, const float* __restrict__ rs) {
  __shared__ __align__(16) unsigned short lds[4][2][256 * 32];  // 128 KiB
  const int tid = threadIdx.x, lane = tid & 63, w = tid >> 6;

  // bijective XCD swizzle (all grids have nwg % 8 == 0)
  const int nx = gridDim.x;
  int bid = blockIdx.y * nx + blockIdx.x;
  bid = (bid & 7) * ((nx * (int)gridDim.y) >> 3) + (bid >> 3);
  const int bn = bid % nx, bm = bid / nx;

  const unsigned short* Ap = A  + (size_t)bm * 256 * lda;
  const unsigned short* Bp = B0 + (size_t)(bm >> 3) * sB + (size_t)bn * 256 * ldb;

  // staging: thread -> (row = tid>>2 within 128-row half, slot = tid&3); source slot
  // pre-swizzled so LDS[r][s] = G[r][s ^ ((r>>1)&3)] with a linear LDS destination.
  const int sr    = tid >> 2;
  const int gslot = (tid & 3) ^ ((sr >> 1) & 3);
  const unsigned short* As0 = Ap + (size_t)sr * lda + gslot * 8;
  const unsigned short* Bs0 = Bp + (size_t)sr * ldb + gslot * 8;

  auto STAGE = [&](int kt) {
    const unsigned short* as = As0 + kt * 32;
    const unsigned short* bs = Bs0 + kt * 32;
    unsigned short* la = &lds[kt & 3][0][0] + tid * 8;
    unsigned short* lb = &lds[kt & 3][1][0] + tid * 8;
    gld_lds16(as,                       la);
    gld_lds16(as + (size_t)128 * lda,   la + 4096);
    gld_lds16(bs,                       lb);
    gld_lds16(bs + (size_t)128 * ldb,   lb + 4096);
  };

  const int wm = w >> 2, wn = w & 3;       // 2 x 4 wave grid
  const int rA = lane & 15;
  const int ssw = ((lane >> 4) ^ ((rA >> 1) & 3)) * 8;  // swizzled k-slot (ushort offset)
  f32x4 acc[8][4] = {};

  auto COMPUTE = [&](int t) {
    const unsigned short* pa = &lds[t & 3][0][0] + (size_t)(wm * 128 + rA) * 32 + ssw;
    const unsigned short* pb = &lds[t & 3][1][0] + (size_t)(wn * 64  + rA) * 32 + ssw;
    // B-frags first, then A-frags staggered between MFMA clusters (progressive lgkmcnt).
    s16x8 b0 = *(const s16x8*)(pb);
    s16x8 b1 = *(const s16x8*)(pb + 512);
    s16x8 b2 = *(const s16x8*)(pb + 1024);
    s16x8 b3 = *(const s16x8*)(pb + 1536);
    s16x8 a0 = *(const s16x8*)(pa);
    s16x8 a1 = *(const s16x8*)(pa + 512);
    s16x8 a2 = *(const s16x8*)(pa + 1024);
    __builtin_amdgcn_s_setprio(1);
#define MM4(ar, i) \
    acc[i][0] = __builtin_amdgcn_mfma_f32_16x16x32_bf16(ar, b0, acc[i][0], 0, 0, 0); \
    acc[i][1] = __builtin_amdgcn_mfma_f32_16x16x32_bf16(ar, b1, acc[i][1], 0, 0, 0); \
    acc[i][2] = __builtin_amdgcn_mfma_f32_16x16x32_bf16(ar, b2, acc[i][2], 0, 0, 0); \
    acc[i][3] = __builtin_amdgcn_mfma_f32_16x16x32_bf16(ar, b3, acc[i][3], 0, 0, 0);
    MM4(a0, 0) s16x8 a3 = *(const s16x8*)(pa + 3 * 512);
    MM4(a1, 1) s16x8 a4 = *(const s16x8*)(pa + 4 * 512);
    MM4(a2, 2) s16x8 a5 = *(const s16x8*)(pa + 5 * 512);
    MM4(a3, 3) s16x8 a6 = *(const s16x8*)(pa + 6 * 512);
    MM4(a4, 4) s16x8 a7 = *(const s16x8*)(pa + 7 * 512);
    MM4(a5, 5)
    MM4(a6, 6)
    MM4(a7, 7)
#undef MM4
    __builtin_amdgcn_s_setprio(0);
  };

  STAGE(0);
  STAGE(1);
#pragma unroll 1
  for (int t = 0; t < TK - 2; ++t) {
    STAGE(t + 2);
    asm volatile("s_waitcnt vmcnt(8)" ::: "memory");
    __builtin_amdgcn_s_barrier();
    COMPUTE(t);
  }
  asm volatile("s_waitcnt vmcnt(4)" ::: "memory");
  __builtin_amdgcn_s_barrier();
  COMPUTE(TK - 2);
  asm volatile("s_waitcnt vmcnt(0)" ::: "memory");
  __builtin_amdgcn_s_barrier();
  COMPUTE(TK - 1);

  // epilogue: C/D layout col = lane&15, row = (lane>>4)*4 + reg (m89/m91)
  const int r0b = bm * 256 + wm * 128 + (lane >> 4) * 4;
  const int c0b = bn * 256 + wn * 64 + rA;
#pragma unroll
  for (int i = 0; i < 8; ++i) {
#pragma unroll
    for (int j = 0; j < 4; ++j) {
      const int cc = c0b + j * 16;
#pragma unroll
      for (int r = 0; r < 4; ++r) {
        const int rr = r0b + i * 16 + r;
        const float val = acc[i][j][r];
        if constexpr (EPI == 0) {
          unsigned short* op = (unsigned short*)((cc >> 10) ? Cv2 : Cv);
          op[(size_t)rr * ldc + (cc & 1023)] = f2b(val + bias[cc]);
        } else if constexpr (EPI == 1) {
          ((unsigned short*)Cv)[(size_t)rr * ldc + cc] = f2b(val);
        } else if constexpr (EPI == 2) {
          // P = exp(s/32) directly (validated r5/r7: absmax unchanged); normalization
          // folds into PV epilogue via rs[row].
          ((unsigned short*)Cv)[(size_t)rr * ldc + cc] = f2b(__expf(val * 0.03125f));
        } else {
          ((float*)Cv)[(size_t)rr * ldc + cc] = val * norms[rr] * rs[rr];
        }
      }
    }
  }
}

// ---------------- row sum of P (unnormalized exp), rs = 1/sum ----------------
__global__ void rowsum(const unsigned short* __restrict__ S, float* __restrict__ rs) {
  const int row = blockIdx.x;
  const int tid = threadIdx.x, lane = tid & 63, w = tid >> 6;
  const unsigned short* sr = S + (size_t)row * SS;
  u16x8 raw = *(const u16x8*)(sr + tid * 8);
  float s = 0.f;
#pragma unroll
  for (int j = 0; j < 8; ++j) s += b2f(raw[j]);
#pragma unroll
  for (int o = 32; o; o >>= 1) s += __shfl_xor(s, o);
  __shared__ float sm[4];
  if (lane == 0) sm[w] = s;
  __syncthreads();
  if (tid == 0) rs[row] = 1.0f / (sm[0] + sm[1] + sm[2] + sm[3]);
}

extern "C" void kernel_launch(void* const* d_in, const int* in_sizes, int n_in,
                              void* d_out, int out_size, void* d_ws, size_t ws_size,
                              hipStream_t stream) {
  (void)in_sizes; (void)n_in; (void)out_size; (void)ws_size;
  const float* X  = (const float*)d_in[0];
  const float* Wq = (const float*)d_in[1];
  const float* bq = (const float*)d_in[2];
  const float* Wv = (const float*)d_in[3];
  const float* bv = (const float*)d_in[4];
  const float* Am = (const float*)d_in[5];

  char* ws = (char*)d_ws;
  size_t off = 0;
  auto alloc = [&](size_t bytes) { char* p = ws + off; off += (bytes + 255) & ~255ull; return p; };
  float* norms          = (float*)alloc((size_t)MROWS * 4);
  float* rs             = (float*)alloc((size_t)MROWS * 4);
  unsigned short* Wqv   = (unsigned short*)alloc((size_t)2 * H * H * 2);  // [Wq; Wv] rows 0..2047
  float* bqv            = (float*)alloc((size_t)2 * H * 4);
  unsigned short* Atb   = (unsigned short*)alloc((size_t)H * H * 2);
  unsigned short* Qb    = (unsigned short*)alloc((size_t)MROWS * H * 2);
  unsigned short* TQb   = (unsigned short*)alloc((size_t)MROWS * H * 2);
  unsigned short* VTb   = (unsigned short*)alloc((size_t)MROWS * H * 2);
  unsigned short* Xs    = (unsigned short*)alloc((size_t)MROWS * H * 2);  // dead after qv GEMM
  unsigned short* Vb    = (unsigned short*)alloc((size_t)MROWS * H * 2);  // dead after transpose
  unsigned short* Sc    = Xs;  // scores [16384][2048] bf16 aliases Xs+Vb (64 MB), live later

  // 1) norms + scaled cast
  norms_cast<<<MROWS / 4, 256, 0, stream>>>(X, Xs, norms);
  // 2) weight casts into concatenated Wqv + bias concat + A^T
  cast_f32_bf16<<<H * H / 1024, 256, 0, stream>>>(Wq, Wqv);
  cast_f32_bf16<<<H * H / 1024, 256, 0, stream>>>(Wv, Wqv + (size_t)H * H);
  hipMemcpyAsync(bqv,     bq, H * sizeof(float), hipMemcpyDeviceToDevice, stream);
  hipMemcpyAsync(bqv + H, bv, H * sizeof(float), hipMemcpyDeviceToDevice, stream);
  transpose_cast_f32<<<dim3(H / 32, H / 32), dim3(32, 8), 0, stream>>>(Am, Atb);
  // 3) merged [q|v] = Xs @ [Wq;Wv]^T + [bq;bv]  (N=2048; split-target epilogue)
  gemm_nt<0, 32><<<dim3(2 * H / 256, MROWS / 256), 512, 0, stream>>>(Xs, H, Wqv, H, 0, Qb, Vb, H, bqv, nullptr, nullptr);
  // 4) vT per batch
  transpose_bf16<<<dim3(H / 32, SS / 32, BB), dim3(32, 8), 0, stream>>>(Vb, VTb);
  // 5) tq = q @ A  (via A^T, NT)
  gemm_nt<1, 32><<<dim3(H / 256, MROWS / 256), 512, 0, stream>>>(Qb, H, Atb, H, 0, TQb, nullptr, H, nullptr, nullptr, nullptr);
  // 6) P = exp(q @ tq^T / 32)  (batched over b via strideB; exp fused in epilogue)
  gemm_nt<2, 32><<<dim3(SS / 256, MROWS / 256), 512, 0, stream>>>(Qb, H, TQb, H, (long)SS * H, Sc, nullptr, SS, nullptr, nullptr, nullptr);
  // 7) rs[row] = 1 / rowsum(P)
  rowsum<<<MROWS, 256, 0, stream>>>(Sc, rs);
  // 8) out = (P @ vT^T) * norm[row] * rs[row]   (K = 2048 -> TK = 64)
  gemm_nt<3, 64><<<dim3(H / 256, MROWS / 256), 512, 0, stream>>>(Sc, SS, VTb, SS, (long)H * SS, d_out, nullptr, H, nullptr, norms, rs);
}